// Round 1
// baseline (10666.366 us; speedup 1.0000x reference)
//
#include <hip/hip_runtime.h>

// ---------------- problem constants ----------------
#define TT   512      // timesteps
#define BB   64       // batch
#define HH1  512      // layer1 hidden
#define HH2  256      // layer2 hidden
#define DD   204      // input dim
#define DXP  224      // x K padded to multiple of 32
#define ST1  744      // LDS row stride (f16 elems) for L1 weights: (224+512)+8, 1488B = 93*16B (odd) -> ~2-way banks
#define ST2  776      // LDS row stride for L2 weights: (512+256)+8, 1552B = 97*16B (odd)
#define G1B  64       // layer1 blocks (8 hidden units each)
#define G2B  32       // layer2 blocks (8 hidden units each)
#define FCN  512      // fc1 width

typedef _Float16 half8 __attribute__((ext_vector_type(8)));
typedef float    f32x4 __attribute__((ext_vector_type(4)));

// A-operand activations stored k-octet tiled: [slot][k>>3][m][k&7] so MFMA A-frag
// loads (lane m = l&15, k-octet = (l>>4)*8) are 16 contiguous 16B loads per lane-quad.
__device__ __align__(16) _Float16 g_h1hi[TT+1][HH1/8][BB][8];
__device__ __align__(16) _Float16 g_h1lo[TT+1][HH1/8][BB][8];
__device__ __align__(16) _Float16 g_xhi[2][DXP/8][BB][8];
__device__ __align__(16) _Float16 g_xlo[2][DXP/8][BB][8];
__device__ __align__(16) _Float16 g_h2hi[2][HH2/8][BB][8];
__device__ __align__(16) _Float16 g_h2lo[2][HH2/8][BB][8];
__device__ float    g_z[BB][FCN];
__device__ unsigned g_ctr1[TT+1];   // layer1 per-step barrier counters (+[TT]=prologue)
__device__ unsigned g_ctr2[TT+1];   // layer2
__device__ unsigned g_prog;         // layer1 progress (steps completed)

__device__ __forceinline__ float sigm(float x){ return 1.0f/(1.0f + __expf(-x)); }
__device__ __forceinline__ float tanha(float x){ return 1.0f - 2.0f/(__expf(2.0f*x) + 1.0f); }

__device__ __forceinline__ void grp_barrier(unsigned* ctr, unsigned target){
  __threadfence();
  __syncthreads();
  if (threadIdx.x == 0){
    __hip_atomic_fetch_add(ctr, 1u, __ATOMIC_RELEASE, __HIP_MEMORY_SCOPE_AGENT);
    while (__hip_atomic_load(ctr, __ATOMIC_ACQUIRE, __HIP_MEMORY_SCOPE_AGENT) < target){}
  }
  __syncthreads();
}

#define MFMA16 __builtin_amdgcn_mfma_f32_16x16x32_f16

__global__ __launch_bounds__(256) void k_scan(
    const float* __restrict__ x,
    const float* __restrict__ Wih1, const float* __restrict__ Whh1,
    const float* __restrict__ bih1, const float* __restrict__ bhh1,
    const float* __restrict__ Wih2, const float* __restrict__ Whh2,
    const float* __restrict__ bih2, const float* __restrict__ bhh2)
{
  // weights as hi/lo f16 pairs, rows permuted: LDS row = tile*16 + nn
  // tile0 rows: [i0..i7, g0..g7], tile1 rows: [f0..f7, o0..o7]  (per block's 8 units)
  __shared__ _Float16 sWhi[32*ST2];
  __shared__ _Float16 sWlo[32*ST2];

  const int tid = threadIdx.x;
  const int bid = blockIdx.x;
  const int l   = tid & 63;
  const int w   = tid >> 6;       // wave id = M-tile (batches w*16..w*16+15)
  const int n   = l & 15;         // B-frag row-in-tile / D col
  const int kq  = l >> 4;         // k-octet selector

  if (bid < G1B){
    // ================= LAYER 1 block: hidden units [bid*8, bid*8+8) =================
    const int ub = bid*8;
    for (int idx = tid; idx < 32*(DXP-DD); idx += 256){     // zero x-pad cols
      int r = idx/(DXP-DD), cc = DD + idx%(DXP-DD);
      sWhi[r*ST1+cc] = (_Float16)0.f; sWlo[r*ST1+cc] = (_Float16)0.f;
    }
    for (int idx = tid; idx < 32*(DD+HH1); idx += 256){
      int r = idx/(DD+HH1), k = idx - r*(DD+HH1);
      int nn = r & 15, tile = r >> 4;
      int gate = tile ? (nn<8 ? 1 : 3) : (nn<8 ? 0 : 2);
      int grow = gate*HH1 + ub + (nn&7);
      float v = (k < DD) ? Wih1[grow*DD + k] : Whh1[grow*HH1 + (k-DD)];
      int dc = (k < DD) ? k : (k - DD + DXP);
      _Float16 hi = (_Float16)v;
      sWhi[r*ST1+dc] = hi;
      sWlo[r*ST1+dc] = (_Float16)(v - (float)hi);
    }
    const int gg0 = (n<8)?0:2, gg1 = (n<8)?1:3;
    const float bias0 = bih1[gg0*HH1+ub+(n&7)] + bhh1[gg0*HH1+ub+(n&7)];
    const float bias1 = bih1[gg1*HH1+ub+(n&7)] + bhh1[gg1*HH1+ub+(n&7)];
    for (int idx = tid; idx < BB*8; idx += 256){            // zero h1 history slot 0 (kt=bid)
      g_h1hi[0][bid][idx>>3][idx&7] = (_Float16)0.f;
      g_h1lo[0][bid][idx>>3][idx&7] = (_Float16)0.f;
    }
    for (int idx = tid; idx < 2*(DXP-DD); idx += 256){      // zero x pads, both slots (row = batch bid)
      int s = idx/(DXP-DD); int d = DD + idx%(DXP-DD);
      g_xhi[s][d>>3][bid][d&7] = (_Float16)0.f;
      g_xlo[s][d>>3][bid][d&7] = (_Float16)0.f;
    }
    if (tid < DD){                                          // split x_0 for batch bid
      float v = x[(bid*TT)*DD + tid];
      _Float16 hi = (_Float16)v;
      g_xhi[0][tid>>3][bid][tid&7] = hi;
      g_xlo[0][tid>>3][bid][tid&7] = (_Float16)(v - (float)hi);
    }
    grp_barrier(&g_ctr1[TT], G1B);

    const int mrow = w*16 + n;
    float cst[4] = {0.f,0.f,0.f,0.f};
    for (int t = 0; t < TT; ++t){
      if (t+1 < TT && tid < DD){                            // produce x split for t+1
        float v = x[(bid*TT + (t+1))*DD + tid];
        _Float16 hi = (_Float16)v;
        g_xhi[(t+1)&1][tid>>3][bid][tid&7] = hi;
        g_xlo[(t+1)&1][tid>>3][bid][tid&7] = (_Float16)(v - (float)hi);
      }
      f32x4 p0a={0.f,0.f,0.f,0.f}, p0b=p0a, p0c=p0a, p1a=p0a, p1b=p0a, p1c=p0a;
      const half8* Axh = (const half8*)g_xhi[t&1];
      const half8* Axl = (const half8*)g_xlo[t&1];
      #pragma unroll
      for (int ks = 0; ks < DXP/32; ++ks){
        half8 ah = Axh[(ks*4+kq)*BB + mrow];
        half8 al = Axl[(ks*4+kq)*BB + mrow];
        int kb = ks*32 + kq*8;
        half8 b0h = *(const half8*)&sWhi[n*ST1 + kb];
        half8 b0l = *(const half8*)&sWlo[n*ST1 + kb];
        half8 b1h = *(const half8*)&sWhi[(16+n)*ST1 + kb];
        half8 b1l = *(const half8*)&sWlo[(16+n)*ST1 + kb];
        p0a = MFMA16(ah,b0h,p0a,0,0,0); p1a = MFMA16(ah,b1h,p1a,0,0,0);
        p0b = MFMA16(ah,b0l,p0b,0,0,0); p1b = MFMA16(ah,b1l,p1b,0,0,0);
        p0c = MFMA16(al,b0h,p0c,0,0,0); p1c = MFMA16(al,b1h,p1c,0,0,0);
      }
      const half8* Ahh = (const half8*)g_h1hi[t];
      const half8* Ahl = (const half8*)g_h1lo[t];
      #pragma unroll
      for (int ks = 0; ks < HH1/32; ++ks){
        half8 ah = Ahh[(ks*4+kq)*BB + mrow];
        half8 al = Ahl[(ks*4+kq)*BB + mrow];
        int kb = DXP + ks*32 + kq*8;
        half8 b0h = *(const half8*)&sWhi[n*ST1 + kb];
        half8 b0l = *(const half8*)&sWlo[n*ST1 + kb];
        half8 b1h = *(const half8*)&sWhi[(16+n)*ST1 + kb];
        half8 b1l = *(const half8*)&sWlo[(16+n)*ST1 + kb];
        p0a = MFMA16(ah,b0h,p0a,0,0,0); p1a = MFMA16(ah,b1h,p1a,0,0,0);
        p0b = MFMA16(ah,b0l,p0b,0,0,0); p1b = MFMA16(ah,b1l,p1b,0,0,0);
        p0c = MFMA16(al,b0h,p0c,0,0,0); p1c = MFMA16(al,b1h,p1c,0,0,0);
      }
      // gates: lanes n<8 hold (i,f) preacts, lanes n>=8 hold (g,o); pair via shfl_xor(8)
      float hv[4];
      #pragma unroll
      for (int r = 0; r < 4; ++r){
        float v0 = ((p0a[r]+p0b[r])+p0c[r]) + bias0;
        float v1 = ((p1a[r]+p1b[r])+p1c[r]) + bias1;
        float av = (n<8) ? sigm(v0) : tanha(v0);   // sig(i) | tanh(g)
        float bv = sigm(v1);                       // sig(f) | sig(o)
        float pa = __shfl_xor(av, 8);
        float cn = bv*cst[r] + av*pa;              // valid on n<8
        float tc = tanha(cn);
        if (n<8) cst[r] = cn;
        float tcx = __shfl_xor(tc, 8);
        hv[r] = bv * tcx;                          // valid on n>=8: sig(o)*tanh(c)
      }
      if (n >= 8){
        int j = n & 7;
        #pragma unroll
        for (int r = 0; r < 4; ++r){
          int m = w*16 + kq*4 + r;
          float h = hv[r];
          _Float16 hi = (_Float16)h;
          g_h1hi[t+1][bid][m][j] = hi;
          g_h1lo[t+1][bid][m][j] = (_Float16)(h - (float)hi);
        }
      }
      __threadfence();
      __syncthreads();
      if (tid == 0){
        __hip_atomic_fetch_add(&g_ctr1[t], 1u, __ATOMIC_RELEASE, __HIP_MEMORY_SCOPE_AGENT);
        while (__hip_atomic_load(&g_ctr1[t], __ATOMIC_ACQUIRE, __HIP_MEMORY_SCOPE_AGENT) < G1B){}
        if (bid == 0)
          __hip_atomic_store(&g_prog, (unsigned)(t+1), __ATOMIC_RELEASE, __HIP_MEMORY_SCOPE_AGENT);
      }
      __syncthreads();
    }
  } else {
    // ================= LAYER 2 block: hidden units [(bid-G1B)*8, ...+8) =================
    const int b2 = bid - G1B;
    const int ub = b2*8;
    for (int idx = tid; idx < 32*(HH1+HH2); idx += 256){
      int r = idx/(HH1+HH2), k = idx - r*(HH1+HH2);
      int nn = r & 15, tile = r >> 4;
      int gate = tile ? (nn<8 ? 1 : 3) : (nn<8 ? 0 : 2);
      int grow = gate*HH2 + ub + (nn&7);
      float v = (k < HH1) ? Wih2[grow*HH1 + k] : Whh2[grow*HH2 + (k-HH1)];
      _Float16 hi = (_Float16)v;
      sWhi[r*ST2+k] = hi;
      sWlo[r*ST2+k] = (_Float16)(v - (float)hi);
    }
    const int gg0 = (n<8)?0:2, gg1 = (n<8)?1:3;
    const float bias0 = bih2[gg0*HH2+ub+(n&7)] + bhh2[gg0*HH2+ub+(n&7)];
    const float bias1 = bih2[gg1*HH2+ub+(n&7)] + bhh2[gg1*HH2+ub+(n&7)];
    for (int idx = tid; idx < BB*8; idx += 256){            // zero h2 slot 0 (kt=b2)
      g_h2hi[0][b2][idx>>3][idx&7] = (_Float16)0.f;
      g_h2lo[0][b2][idx>>3][idx&7] = (_Float16)0.f;
    }
    grp_barrier(&g_ctr2[TT], G2B);

    const int mrow = w*16 + n;
    float cst[4] = {0.f,0.f,0.f,0.f};
    for (int t = 0; t < TT; ++t){
      if (tid == 0){   // wait for layer1 to publish h1_t (= hist slot t+1)
        while (__hip_atomic_load(&g_prog, __ATOMIC_ACQUIRE, __HIP_MEMORY_SCOPE_AGENT) < (unsigned)(t+1)){}
      }
      __syncthreads();
      f32x4 p0a={0.f,0.f,0.f,0.f}, p0b=p0a, p0c=p0a, p1a=p0a, p1b=p0a, p1c=p0a;
      const half8* Ahh = (const half8*)g_h1hi[t+1];
      const half8* Ahl = (const half8*)g_h1lo[t+1];
      #pragma unroll
      for (int ks = 0; ks < HH1/32; ++ks){
        half8 ah = Ahh[(ks*4+kq)*BB + mrow];
        half8 al = Ahl[(ks*4+kq)*BB + mrow];
        int kb = ks*32 + kq*8;
        half8 b0h = *(const half8*)&sWhi[n*ST2 + kb];
        half8 b0l = *(const half8*)&sWlo[n*ST2 + kb];
        half8 b1h = *(const half8*)&sWhi[(16+n)*ST2 + kb];
        half8 b1l = *(const half8*)&sWlo[(16+n)*ST2 + kb];
        p0a = MFMA16(ah,b0h,p0a,0,0,0); p1a = MFMA16(ah,b1h,p1a,0,0,0);
        p0b = MFMA16(ah,b0l,p0b,0,0,0); p1b = MFMA16(ah,b1l,p1b,0,0,0);
        p0c = MFMA16(al,b0h,p0c,0,0,0); p1c = MFMA16(al,b1h,p1c,0,0,0);
      }
      const half8* A2h = (const half8*)g_h2hi[t&1];
      const half8* A2l = (const half8*)g_h2lo[t&1];
      #pragma unroll
      for (int ks = 0; ks < HH2/32; ++ks){
        half8 ah = A2h[(ks*4+kq)*BB + mrow];
        half8 al = A2l[(ks*4+kq)*BB + mrow];
        int kb = HH1 + ks*32 + kq*8;
        half8 b0h = *(const half8*)&sWhi[n*ST2 + kb];
        half8 b0l = *(const half8*)&sWlo[n*ST2 + kb];
        half8 b1h = *(const half8*)&sWhi[(16+n)*ST2 + kb];
        half8 b1l = *(const half8*)&sWlo[(16+n)*ST2 + kb];
        p0a = MFMA16(ah,b0h,p0a,0,0,0); p1a = MFMA16(ah,b1h,p1a,0,0,0);
        p0b = MFMA16(ah,b0l,p0b,0,0,0); p1b = MFMA16(ah,b1l,p1b,0,0,0);
        p0c = MFMA16(al,b0h,p0c,0,0,0); p1c = MFMA16(al,b1h,p1c,0,0,0);
      }
      float hv[4];
      #pragma unroll
      for (int r = 0; r < 4; ++r){
        float v0 = ((p0a[r]+p0b[r])+p0c[r]) + bias0;
        float v1 = ((p1a[r]+p1b[r])+p1c[r]) + bias1;
        float av = (n<8) ? sigm(v0) : tanha(v0);
        float bv = sigm(v1);
        float pa = __shfl_xor(av, 8);
        float cn = bv*cst[r] + av*pa;
        float tc = tanha(cn);
        if (n<8) cst[r] = cn;
        float tcx = __shfl_xor(tc, 8);
        hv[r] = bv * tcx;
      }
      if (n >= 8){
        int j = n & 7;
        #pragma unroll
        for (int r = 0; r < 4; ++r){
          int m = w*16 + kq*4 + r;
          float h = hv[r];
          _Float16 hi = (_Float16)h;
          g_h2hi[(t+1)&1][b2][m][j] = hi;
          g_h2lo[(t+1)&1][b2][m][j] = (_Float16)(h - (float)hi);
        }
      }
      __threadfence();
      __syncthreads();
      if (tid == 0){
        __hip_atomic_fetch_add(&g_ctr2[t], 1u, __ATOMIC_RELEASE, __HIP_MEMORY_SCOPE_AGENT);
        while (__hip_atomic_load(&g_ctr2[t], __ATOMIC_ACQUIRE, __HIP_MEMORY_SCOPE_AGENT) < G2B){}
      }
      __syncthreads();
    }
  }
}

// z = relu(h2_last @ Wfc1^T + bfc1); block b -> cols [8b, 8b+8)
__global__ __launch_bounds__(256) void k_fc1(const float* __restrict__ Wfc1, const float* __restrict__ bfc1){
  int b = blockIdx.x;
  for (int task = threadIdx.x; task < 512; task += 256){
    int m = task >> 3, cc = b*8 + (task & 7);
    float acc = bfc1[cc];
    const float* wr = &Wfc1[cc*HH2];
    for (int k = 0; k < HH2; ++k){
      float hvv = (float)g_h2hi[0][k>>3][m][k&7] + (float)g_h2lo[0][k>>3][m][k&7];
      acc += hvv * wr[k];
    }
    g_z[m][cc] = fmaxf(acc, 0.f);
  }
}

// out = z @ Wfc2^T + bfc2; also reset barrier state for the next call
__global__ __launch_bounds__(256) void k_fc2(const float* __restrict__ Wfc2, const float* __restrict__ bfc2,
                                             float* __restrict__ out){
  for (int task = threadIdx.x; task < BB*7; task += 256){
    int m = task / 7, oc = task % 7;
    float acc = bfc2[oc];
    const float* wr = &Wfc2[oc*FCN];
    const float* zr = &g_z[m][0];
    for (int k = 0; k < FCN; ++k) acc += zr[k]*wr[k];
    out[m*7 + oc] = acc;
  }
  for (int i = threadIdx.x; i < TT+1; i += 256){ g_ctr1[i] = 0u; g_ctr2[i] = 0u; }
  if (threadIdx.x == 0) g_prog = 0u;
}

extern "C" void kernel_launch(void* const* d_in, const int* in_sizes, int n_in,
                              void* d_out, int out_size, void* d_ws, size_t ws_size,
                              hipStream_t stream){
  (void)in_sizes; (void)n_in; (void)out_size; (void)d_ws; (void)ws_size;
  const float* x    = (const float*)d_in[0];
  const float* Wih1 = (const float*)d_in[1];
  const float* Whh1 = (const float*)d_in[2];
  const float* bih1 = (const float*)d_in[3];
  const float* bhh1 = (const float*)d_in[4];
  const float* Wih2 = (const float*)d_in[5];
  const float* Whh2 = (const float*)d_in[6];
  const float* bih2 = (const float*)d_in[7];
  const float* bhh2 = (const float*)d_in[8];
  const float* Wfc1 = (const float*)d_in[9];
  const float* bfc1 = (const float*)d_in[10];
  const float* Wfc2 = (const float*)d_in[11];
  const float* bfc2 = (const float*)d_in[12];

  hipLaunchKernelGGL(k_scan, dim3(G1B+G2B), dim3(256), 0, stream,
                     x, Wih1, Whh1, bih1, bhh1, Wih2, Whh2, bih2, bhh2);
  hipLaunchKernelGGL(k_fc1, dim3(FCN/8), dim3(256), 0, stream, Wfc1, bfc1);
  hipLaunchKernelGGL(k_fc2, dim3(1), dim3(256), 0, stream, Wfc2, bfc2, (float*)d_out);
}

// Round 2
// 7411.016 us; speedup vs baseline: 1.4393x; 1.4393x over previous
//
#include <hip/hip_runtime.h>

// ---------------- problem constants ----------------
#define TT   512
#define BB   64
#define HH1  512
#define HH2  256
#define DD   204
#define DXP  224          // x K padded to x32
#define KO_X (DXP/8)      // 28 k-octets for x
#define G1B  32           // layer1 blocks (16 units each)
#define G2B  32           // layer2 blocks (8 units each)
#define NBLK (G1B+G2B)
#define ST1R 520          // LDS stride (halfs) for Whh1 rows (512+8)
#define ST2R 776          // LDS stride for [Wih2|Whh2] rows (768+8)
#define STXR 232          // LDS stride for Wih1 rows in xg GEMM (224+8)
#define FCN  512

typedef _Float16 half8 __attribute__((ext_vector_type(8)));
typedef float    f32x4 __attribute__((ext_vector_type(4)));

// activations in MFMA-A layout: [k-octet][row][8]
__device__ __align__(16) _Float16 g_xAhi[KO_X][TT*BB][8];
__device__ __align__(16) _Float16 g_xAlo[KO_X][TT*BB][8];
__device__ float    g_xg[TT][G1B][BB][64];          // precomputed x@Wih1 (permuted cols)
__device__ __align__(16) _Float16 g_h1hi[TT+1][HH1/8][BB][8];
__device__ __align__(16) _Float16 g_h1lo[TT+1][HH1/8][BB][8];
__device__ __align__(16) _Float16 g_h2hi[TT+1][HH2/8][BB][8];
__device__ __align__(16) _Float16 g_h2lo[TT+1][HH2/8][BB][8];
__device__ float    g_z[BB][FCN];
__device__ unsigned g_ctr1[TT+1];   // [t]: L1 blocks done with step t; [TT]: prologue
__device__ unsigned g_ctr2[TT+1];

__device__ __forceinline__ float sigm(float x){ return 1.0f/(1.0f + __expf(-x)); }
__device__ __forceinline__ float tanha(float x){ return 1.0f - 2.0f/(__expf(2.0f*x) + 1.0f); }

__device__ __forceinline__ void awrite(unsigned* p, unsigned v){
  __hip_atomic_store(p, v, __ATOMIC_RELAXED, __HIP_MEMORY_SCOPE_AGENT);
}
// relaxed spin + one acquire (L1/L2 invalidate) on success
__device__ __forceinline__ void wait_ctr(unsigned* c, unsigned target){
  while (__hip_atomic_load(c, __ATOMIC_RELAXED, __HIP_MEMORY_SCOPE_AGENT) < target)
    __builtin_amdgcn_s_sleep(1);
  (void)__hip_atomic_load(c, __ATOMIC_ACQUIRE, __HIP_MEMORY_SCOPE_AGENT);
}
__device__ __forceinline__ unsigned short h16(_Float16 h){
  union { _Float16 f; unsigned short u; } cv; cv.f = h; return cv.u;
}

#define MFMA16 __builtin_amdgcn_mfma_f32_16x16x32_f16

// ---------- split x into hi/lo f16 planes, MFMA-A layout (row = t*BB+b) ----------
__global__ __launch_bounds__(256) void k_split(const float* __restrict__ x){
  int t = blockIdx.x;
  for (int idx = threadIdx.x; idx < BB*DXP; idx += 256){
    int b = idx / DXP, d = idx - b*DXP;
    float v = (d < DD) ? x[(b*TT + t)*DD + d] : 0.f;
    _Float16 hi = (_Float16)v;
    _Float16 lo = (_Float16)(v - (float)hi);
    g_xAhi[d>>3][t*BB + b][d&7] = hi;
    g_xAlo[d>>3][t*BB + b][d&7] = lo;
  }
}

// ---------- xg = x @ Wih1^T, output permuted to scan layout ----------
// grid: 32 blk x 8 t-chunks; block: 256 thr, wave w owns N-tile w (16 rows), all 64 b.
__global__ __launch_bounds__(256) void k_xg(const float* __restrict__ Wih1){
  __shared__ _Float16 sBh[64*STXR];
  __shared__ _Float16 sBl[64*STXR];
  const int tid = threadIdx.x;
  const int blk = blockIdx.x & 31, tc = blockIdx.x >> 5;
  for (int idx = tid; idx < 64*DXP; idx += 256){
    int r = idx / DXP, k = idx - r*DXP;
    int tile = r >> 4, nn = r & 15;
    int gate = (tile&1) + ((nn>>3)<<1);
    int unit = ((tile>>1)<<3) + (nn&7);
    int grow = gate*HH1 + blk*16 + unit;
    float v = (k < DD) ? Wih1[grow*DD + k] : 0.f;
    _Float16 hi = (_Float16)v;
    sBh[r*STXR + k] = hi;
    sBl[r*STXR + k] = (_Float16)(v - (float)hi);
  }
  __syncthreads();
  const int l = tid & 63, w = tid >> 6, n = l & 15, kq = l >> 4;
  for (int t = tc*64; t < tc*64 + 64; ++t){
    f32x4 a0[4], a1[4], a2[4];
    #pragma unroll
    for (int mt = 0; mt < 4; ++mt){ a0[mt]=(f32x4){0,0,0,0}; a1[mt]=a0[mt]; a2[mt]=a0[mt]; }
    #pragma unroll
    for (int ks = 0; ks < 7; ++ks){
      int o = ks*4 + kq, kb = ks*32 + kq*8;
      half8 bh = *(const half8*)&sBh[(w*16+n)*STXR + kb];
      half8 bl = *(const half8*)&sBl[(w*16+n)*STXR + kb];
      #pragma unroll
      for (int mt = 0; mt < 4; ++mt){
        half8 ah = *(const half8*)&g_xAhi[o][t*BB + mt*16 + n][0];
        half8 al = *(const half8*)&g_xAlo[o][t*BB + mt*16 + n][0];
        a0[mt] = MFMA16(ah, bh, a0[mt], 0,0,0);
        a1[mt] = MFMA16(ah, bl, a1[mt], 0,0,0);
        a2[mt] = MFMA16(al, bh, a2[mt], 0,0,0);
      }
    }
    #pragma unroll
    for (int mt = 0; mt < 4; ++mt)
      #pragma unroll
      for (int rr = 0; rr < 4; ++rr){
        int b = mt*16 + kq*4 + rr;
        g_xg[t][blk][b][w*16 + n] = (a0[mt][rr] + a1[mt][rr]) + a2[mt][rr];
      }
  }
}

// ---------- the sequential scan: 32 L1 blocks + 32 L2 blocks ----------
__global__ __launch_bounds__(256) void k_scan(
    const float* __restrict__ Whh1, const float* __restrict__ bih1, const float* __restrict__ bhh1,
    const float* __restrict__ Wih2, const float* __restrict__ Whh2,
    const float* __restrict__ bih2, const float* __restrict__ bhh2)
{
  __shared__ _Float16 sWhi[64*ST1R];
  __shared__ _Float16 sWlo[64*ST1R];

  const int tid = threadIdx.x;
  const int bid = blockIdx.x;
  const int l   = tid & 63;
  const int w   = tid >> 6;      // wave = M-tile (batches w*16..)
  const int n   = l & 15;
  const int kq  = l >> 4;
  const int mrow = w*16 + n;
  const int mout = w*16 + kq*4;  // + r

  // ---- zero initial states (write-through so all XCDs see them) ----
  {
    int gtid = bid*256 + tid;
    unsigned* z1h = (unsigned*)&g_h1hi[0][0][0][0];
    unsigned* z1l = (unsigned*)&g_h1lo[0][0][0][0];
    if (gtid < (HH1*BB)/2){ awrite(z1h+gtid, 0u); awrite(z1l+gtid, 0u); }
    unsigned* z2h = (unsigned*)&g_h2hi[0][0][0][0];
    unsigned* z2l = (unsigned*)&g_h2lo[0][0][0][0];
    if (gtid < (HH2*BB)/2){ awrite(z2h+gtid, 0u); awrite(z2l+gtid, 0u); }
  }

  if (bid < G1B){
    // ============ LAYER 1: units [bid*16, bid*16+16), 4 N-tiles ============
    const int ub = bid*16;
    for (int idx = tid; idx < 64*HH1; idx += 256){
      int r = idx >> 9, k = idx & 511;
      int tile = r >> 4, nn = r & 15;
      int gate = (tile&1) + ((nn>>3)<<1);
      int unit = ((tile>>1)<<3) + (nn&7);
      int grow = gate*HH1 + ub + unit;
      float v = Whh1[grow*HH1 + k];
      _Float16 hi = (_Float16)v;
      sWhi[r*ST1R + k] = hi;
      sWlo[r*ST1R + k] = (_Float16)(v - (float)hi);
    }
    float bias[4];
    #pragma unroll
    for (int tl = 0; tl < 4; ++tl){
      int gate = (tl&1) + ((n>>3)<<1);
      int unit = ((tl>>1)<<3) + (n&7);
      int gi = gate*HH1 + ub + unit;
      bias[tl] = bih1[gi] + bhh1[gi];
    }
    asm volatile("s_waitcnt vmcnt(0)" ::: "memory");
    __syncthreads();
    if (tid == 0){
      __hip_atomic_fetch_add(&g_ctr1[TT], 1u, __ATOMIC_RELAXED, __HIP_MEMORY_SCOPE_AGENT);
      wait_ctr(&g_ctr1[TT], NBLK);
    }
    __syncthreads();

    float cst[2][4] = {{0,0,0,0},{0,0,0,0}};
    for (int t = 0; t < TT; ++t){
      if (t > 0){
        if (tid == 0) wait_ctr(&g_ctr1[t-1], G1B);
        __syncthreads();
      }
      float xgv[4][4];
      const float* xgp = &g_xg[t][bid][0][0];
      #pragma unroll
      for (int tl = 0; tl < 4; ++tl)
        #pragma unroll
        for (int r = 0; r < 4; ++r)
          xgv[tl][r] = xgp[(mout + r)*64 + tl*16 + n];

      f32x4 a0[4], a1[4], a2[4];
      #pragma unroll
      for (int tl = 0; tl < 4; ++tl){ a0[tl]=(f32x4){0,0,0,0}; a1[tl]=a0[tl]; a2[tl]=a0[tl]; }
      const half8* Ah = (const half8*)&g_h1hi[t][0][0][0];
      const half8* Al = (const half8*)&g_h1lo[t][0][0][0];
      #pragma unroll 4
      for (int ks = 0; ks < 16; ++ks){
        half8 ah = Ah[(ks*4+kq)*BB + mrow];
        half8 al = Al[(ks*4+kq)*BB + mrow];
        int kb = ks*32 + kq*8;
        #pragma unroll
        for (int tl = 0; tl < 4; ++tl){
          half8 bh = *(const half8*)&sWhi[(tl*16+n)*ST1R + kb];
          half8 bl = *(const half8*)&sWlo[(tl*16+n)*ST1R + kb];
          a0[tl] = MFMA16(ah, bh, a0[tl], 0,0,0);
          a1[tl] = MFMA16(ah, bl, a1[tl], 0,0,0);
          a2[tl] = MFMA16(al, bh, a2[tl], 0,0,0);
        }
      }
      #pragma unroll
      for (int j = 0; j < 2; ++j){
        #pragma unroll
        for (int r = 0; r < 4; ++r){
          float v0 = ((a0[2*j][r]+a1[2*j][r])+a2[2*j][r]) + bias[2*j]   + xgv[2*j][r];
          float v1 = ((a0[2*j+1][r]+a1[2*j+1][r])+a2[2*j+1][r]) + bias[2*j+1] + xgv[2*j+1][r];
          float av = (n < 8) ? sigm(v0) : tanha(v0);
          float bv = sigm(v1);
          float pa = __shfl_xor(av, 8);
          float cn = bv*cst[j][r] + av*pa;
          float tc = tanha(cn);
          if (n < 8) cst[j][r] = cn;
          float tcx = __shfl_xor(tc, 8);
          float hv = bv * tcx;                 // valid on n>=8
          float hx = __shfl_xor(hv, 1);
          if (n >= 8 && !(n & 1)){
            _Float16 h0 = (_Float16)hv; _Float16 l0 = (_Float16)(hv - (float)h0);
            _Float16 h1v = (_Float16)hx; _Float16 l1 = (_Float16)(hx - (float)h1v);
            unsigned hw = (unsigned)h16(h0) | ((unsigned)h16(h1v) << 16);
            unsigned lw = (unsigned)h16(l0) | ((unsigned)h16(l1) << 16);
            int m = mout + r;
            awrite((unsigned*)&g_h1hi[t+1][bid*2+j][m][0] + ((n&7)>>1), hw);
            awrite((unsigned*)&g_h1lo[t+1][bid*2+j][m][0] + ((n&7)>>1), lw);
          }
        }
      }
      asm volatile("s_waitcnt vmcnt(0)" ::: "memory");
      __syncthreads();
      if (tid == 0)
        __hip_atomic_fetch_add(&g_ctr1[t], 1u, __ATOMIC_RELAXED, __HIP_MEMORY_SCOPE_AGENT);
    }
  } else {
    // ============ LAYER 2: units [(bid-32)*8, ..+8), 2 N-tiles ============
    const int b2 = bid - G1B;
    const int ub = b2*8;
    for (int idx = tid; idx < 32*768; idx += 256){
      int r = idx / 768, k = idx - r*768;
      int tile = r >> 4, nn = r & 15;
      int gate = (tile&1) + ((nn>>3)<<1);
      int grow = gate*HH2 + ub + (nn&7);
      float v = (k < HH1) ? Wih2[grow*HH1 + k] : Whh2[grow*HH2 + (k-HH1)];
      _Float16 hi = (_Float16)v;
      sWhi[r*ST2R + k] = hi;
      sWlo[r*ST2R + k] = (_Float16)(v - (float)hi);
    }
    float bias[2];
    #pragma unroll
    for (int tl = 0; tl < 2; ++tl){
      int gate = (tl&1) + ((n>>3)<<1);
      int gi = gate*HH2 + ub + (n&7);
      bias[tl] = bih2[gi] + bhh2[gi];
    }
    asm volatile("s_waitcnt vmcnt(0)" ::: "memory");
    __syncthreads();
    if (tid == 0){
      __hip_atomic_fetch_add(&g_ctr1[TT], 1u, __ATOMIC_RELAXED, __HIP_MEMORY_SCOPE_AGENT);
      wait_ctr(&g_ctr1[TT], NBLK);
    }
    __syncthreads();

    float cst[4] = {0,0,0,0};
    for (int t = 0; t < TT; ++t){
      if (tid == 0){
        wait_ctr(&g_ctr1[t], G1B);               // h1_t (= slot t+1) published
        if (t > 0) wait_ctr(&g_ctr2[t-1], G2B);  // h2_t published
      }
      __syncthreads();

      f32x4 a0[2], a1[2], a2[2];
      #pragma unroll
      for (int tl = 0; tl < 2; ++tl){ a0[tl]=(f32x4){0,0,0,0}; a1[tl]=a0[tl]; a2[tl]=a0[tl]; }
      const half8* Ah = (const half8*)&g_h1hi[t+1][0][0][0];
      const half8* Al = (const half8*)&g_h1lo[t+1][0][0][0];
      #pragma unroll 4
      for (int ks = 0; ks < 16; ++ks){
        half8 ah = Ah[(ks*4+kq)*BB + mrow];
        half8 al = Al[(ks*4+kq)*BB + mrow];
        int kb = ks*32 + kq*8;
        #pragma unroll
        for (int tl = 0; tl < 2; ++tl){
          half8 bh = *(const half8*)&sWhi[(tl*16+n)*ST2R + kb];
          half8 bl = *(const half8*)&sWlo[(tl*16+n)*ST2R + kb];
          a0[tl] = MFMA16(ah, bh, a0[tl], 0,0,0);
          a1[tl] = MFMA16(ah, bl, a1[tl], 0,0,0);
          a2[tl] = MFMA16(al, bh, a2[tl], 0,0,0);
        }
      }
      const half8* Bh = (const half8*)&g_h2hi[t][0][0][0];
      const half8* Bl = (const half8*)&g_h2lo[t][0][0][0];
      #pragma unroll 4
      for (int ks = 0; ks < 8; ++ks){
        half8 ah = Bh[(ks*4+kq)*BB + mrow];
        half8 al = Bl[(ks*4+kq)*BB + mrow];
        int kb = HH1 + ks*32 + kq*8;
        #pragma unroll
        for (int tl = 0; tl < 2; ++tl){
          half8 bh = *(const half8*)&sWhi[(tl*16+n)*ST2R + kb];
          half8 bl = *(const half8*)&sWlo[(tl*16+n)*ST2R + kb];
          a0[tl] = MFMA16(ah, bh, a0[tl], 0,0,0);
          a1[tl] = MFMA16(ah, bl, a1[tl], 0,0,0);
          a2[tl] = MFMA16(al, bh, a2[tl], 0,0,0);
        }
      }
      #pragma unroll
      for (int r = 0; r < 4; ++r){
        float v0 = ((a0[0][r]+a1[0][r])+a2[0][r]) + bias[0];
        float v1 = ((a0[1][r]+a1[1][r])+a2[1][r]) + bias[1];
        float av = (n < 8) ? sigm(v0) : tanha(v0);
        float bv = sigm(v1);
        float pa = __shfl_xor(av, 8);
        float cn = bv*cst[r] + av*pa;
        float tc = tanha(cn);
        if (n < 8) cst[r] = cn;
        float tcx = __shfl_xor(tc, 8);
        float hv = bv * tcx;
        float hx = __shfl_xor(hv, 1);
        if (n >= 8 && !(n & 1)){
          _Float16 h0 = (_Float16)hv; _Float16 l0 = (_Float16)(hv - (float)h0);
          _Float16 h1v = (_Float16)hx; _Float16 l1 = (_Float16)(hx - (float)h1v);
          unsigned hw = (unsigned)h16(h0) | ((unsigned)h16(h1v) << 16);
          unsigned lw = (unsigned)h16(l0) | ((unsigned)h16(l1) << 16);
          int m = mout + r;
          awrite((unsigned*)&g_h2hi[t+1][b2][m][0] + ((n&7)>>1), hw);
          awrite((unsigned*)&g_h2lo[t+1][b2][m][0] + ((n&7)>>1), lw);
        }
      }
      asm volatile("s_waitcnt vmcnt(0)" ::: "memory");
      __syncthreads();
      if (tid == 0)
        __hip_atomic_fetch_add(&g_ctr2[t], 1u, __ATOMIC_RELAXED, __HIP_MEMORY_SCOPE_AGENT);
    }
  }
}

// z = relu(h2_T @ Wfc1^T + bfc1)
__global__ __launch_bounds__(256) void k_fc1(const float* __restrict__ Wfc1, const float* __restrict__ bfc1){
  int b = blockIdx.x;
  for (int task = threadIdx.x; task < 512; task += 256){
    int m = task >> 3, cc = b*8 + (task & 7);
    float acc = bfc1[cc];
    const float* wr = &Wfc1[cc*HH2];
    for (int k = 0; k < HH2; ++k){
      float hvv = (float)g_h2hi[TT][k>>3][m][k&7] + (float)g_h2lo[TT][k>>3][m][k&7];
      acc += hvv * wr[k];
    }
    g_z[m][cc] = fmaxf(acc, 0.f);
  }
}

__global__ __launch_bounds__(256) void k_fc2(const float* __restrict__ Wfc2, const float* __restrict__ bfc2,
                                             float* __restrict__ out){
  for (int task = threadIdx.x; task < BB*7; task += 256){
    int m = task / 7, oc = task % 7;
    float acc = bfc2[oc];
    const float* wr = &Wfc2[oc*FCN];
    const float* zr = &g_z[m][0];
    for (int k = 0; k < FCN; ++k) acc += zr[k]*wr[k];
    out[m*7 + oc] = acc;
  }
  for (int i = threadIdx.x; i < TT+1; i += 256){ g_ctr1[i] = 0u; g_ctr2[i] = 0u; }
}

extern "C" void kernel_launch(void* const* d_in, const int* in_sizes, int n_in,
                              void* d_out, int out_size, void* d_ws, size_t ws_size,
                              hipStream_t stream){
  (void)in_sizes; (void)n_in; (void)out_size; (void)d_ws; (void)ws_size;
  const float* x    = (const float*)d_in[0];
  const float* Wih1 = (const float*)d_in[1];
  const float* Whh1 = (const float*)d_in[2];
  const float* bih1 = (const float*)d_in[3];
  const float* bhh1 = (const float*)d_in[4];
  const float* Wih2 = (const float*)d_in[5];
  const float* Whh2 = (const float*)d_in[6];
  const float* bih2 = (const float*)d_in[7];
  const float* bhh2 = (const float*)d_in[8];
  const float* Wfc1 = (const float*)d_in[9];
  const float* bfc1 = (const float*)d_in[10];
  const float* Wfc2 = (const float*)d_in[11];
  const float* bfc2 = (const float*)d_in[12];

  hipLaunchKernelGGL(k_split, dim3(TT), dim3(256), 0, stream, x);
  hipLaunchKernelGGL(k_xg,    dim3(G1B*8), dim3(256), 0, stream, Wih1);
  hipLaunchKernelGGL(k_scan,  dim3(NBLK), dim3(256), 0, stream,
                     Whh1, bih1, bhh1, Wih2, Whh2, bih2, bhh2);
  hipLaunchKernelGGL(k_fc1,   dim3(FCN/8), dim3(256), 0, stream, Wfc1, bfc1);
  hipLaunchKernelGGL(k_fc2,   dim3(1), dim3(256), 0, stream, Wfc2, bfc2, (float*)d_out);
}